// Round 1
// baseline (45.468 us; speedup 1.0000x reference)
//
#include <hip/hip_runtime.h>
#include <hip/hip_bf16.h>

#define TOKENS 2048
#define IN_F   4096
#define OUT_F  4096

typedef __bf16 bf16x8 __attribute__((ext_vector_type(8)));
typedef float  f32x4  __attribute__((ext_vector_type(4)));

union U16 { uint4 u; bf16x8 v; };

// manual round-to-nearest-even fp32 -> bf16 (inputs are normal floats, no NaN)
__device__ __forceinline__ unsigned int f2bf(float f) {
    unsigned int b = __float_as_uint(f);
    b += 0x7fffu + ((b >> 16) & 1u);
    return b >> 16;
}
__device__ __forceinline__ unsigned int pk(float lo, float hi) {
    return f2bf(lo) | (f2bf(hi) << 16);
}

// ---------------------------------------------------------------------------
// Prepass: x [2048][4096] fp32 row-major  ->  xb [256 cb][2048 tok][16] bf16
// (block-column-major panels so the sparse gather reads contiguous 512B runs)
// grid = 2048 blocks (32 token-tiles x 64 feat-tiles), 256 threads
// ---------------------------------------------------------------------------
__global__ __launch_bounds__(256)
void xprep_kernel(const float* __restrict__ x, uint4* __restrict__ xb) {
    __shared__ float tl[64][65];   // 64 tok x 64 feat tile, +1 pad
    const int tid  = threadIdx.x;
    const int tt   = blockIdx.x & 31;   // token tile (2048/64 = 32)
    const int ft   = blockIdx.x >> 5;   // feat tile  (4096/64 = 64)
    const int tok0 = tt * 64;
    const int f0   = ft * 64;

    const float4* xf4 = reinterpret_cast<const float4*>(x);
#pragma unroll
    for (int p = 0; p < 4; ++p) {
        int r  = p * 16 + (tid >> 4);
        int c4 = tid & 15;
        float4 v = xf4[(size_t)(tok0 + r) * (IN_F / 4) + (f0 / 4) + c4];
        tl[r][c4 * 4 + 0] = v.x; tl[r][c4 * 4 + 1] = v.y;
        tl[r][c4 * 4 + 2] = v.z; tl[r][c4 * 4 + 3] = v.w;
    }
    __syncthreads();
#pragma unroll
    for (int p = 0; p < 2; ++p) {
        int j   = p * 256 + tid;      // 0..511
        int cb  = j >> 7;             // 0..3
        int tok = (j >> 1) & 63;
        int hi  = j & 1;
        int fb  = cb * 16 + hi * 8;
        uint4 o;
        o.x = pk(tl[tok][fb + 0], tl[tok][fb + 1]);
        o.y = pk(tl[tok][fb + 2], tl[tok][fb + 3]);
        o.z = pk(tl[tok][fb + 4], tl[tok][fb + 5]);
        o.w = pk(tl[tok][fb + 6], tl[tok][fb + 7]);
        xb[((size_t)(f0 / 16 + cb) * TOKENS + tok0 + tok) * 2 + hi] = o;
    }
}

// ---------------------------------------------------------------------------
// Main: one workgroup = 1 block-row x 256 tokens. 4 waves x (4 M-tiles of 16).
// Row weights staged to LDS as pre-permuted bf16 MFMA B-fragments.
// grid = 256 rows x 8 token tiles = 2048;  tile = bid&7 pins tile->XCD.
// ---------------------------------------------------------------------------
template <bool BFX>
__global__ __launch_bounds__(256)
void bsl_kernel(const void* __restrict__ xsrc,
                const float* __restrict__ sb,
                const int* __restrict__ rowptr,
                const int* __restrict__ colidx,
                const float* __restrict__ bias,
                float* __restrict__ out)
{
    __shared__ uint4 wlds[1024];   // 16 k-tiles x 64 lane-fragments x 16B = 16KB
    __shared__ int   cols_s[32];

    const int bid  = blockIdx.x;
    const int tile = bid & 7;
    const int row  = bid >> 3;
    const int tid  = threadIdx.x;

    const int row_start = rowptr[row];
    int nb = rowptr[row + 1] - row_start;
    if (nb > 32) nb = 32;
    if (nb < 0)  nb = 0;

    if (tid < 32) cols_s[tid] = (tid < nb) ? colidx[row_start + tid] : 0;

    // stage weights: fragment fg = t*64 + f;  f -> (blk = 2t + (f>>5), o = f&15, hi = (f>>4)&1)
    // contents: bf16 of W[blk][o][hi*8 + 0..7]   (B[k][n] = W[n][k])
#pragma unroll
    for (int j = 0; j < 4; ++j) {
        int fg = j * 256 + tid;
        int bl = ((fg >> 6) << 1) | ((fg >> 5) & 1);
        uint4 w = make_uint4(0u, 0u, 0u, 0u);
        if (bl < nb) {
            const float4* s4 = reinterpret_cast<const float4*>(
                sb + (size_t)(row_start + bl) * 256 + (fg & 15) * 16 + ((fg >> 4) & 1) * 8);
            float4 a = s4[0], b = s4[1];
            w.x = pk(a.x, a.y); w.y = pk(a.z, a.w);
            w.z = pk(b.x, b.y); w.w = pk(b.z, b.w);
        }
        wlds[fg] = w;
    }
    __syncthreads();

    const int lane = tid & 63;
    const int wid  = tid >> 6;
    const int orow = lane & 15;        // A-row (token) / D-col (feat)
    const int kg   = lane >> 4;        // 0..3
    const int hi   = kg & 1;
    const int bsel = lane >> 5;        // which of the 2 blocks in this k-tile
    const int tok_base = tile * 256 + wid * 64;

    const float bv = bias[(row << 4) + orow];
    f32x4 acc0 = {bv, bv, bv, bv};
    f32x4 acc1 = acc0, acc2 = acc0, acc3 = acc0;

    const int NT = (nb + 1) >> 1;
    for (int t = 0; t < NT; ++t) {
        U16 bw; bw.u = wlds[(t << 6) + lane];
        const int c = cols_s[2 * t + bsel];
        U16 a0, a1, a2, a3;
        if (BFX) {
            const uint4* xb = reinterpret_cast<const uint4*>(xsrc);
            size_t base = ((size_t)c * TOKENS + tok_base + orow) * 2 + hi;
            a0.u = xb[base];
            a1.u = xb[base + 32];    // +16 tokens
            a2.u = xb[base + 64];
            a3.u = xb[base + 96];
        } else {
            const float* xf = reinterpret_cast<const float*>(xsrc);
            size_t rb = (size_t)(tok_base + orow) * IN_F + c * 16 + hi * 8;
#pragma unroll
            for (int m = 0; m < 4; ++m) {
                const float4* p = reinterpret_cast<const float4*>(xf + rb + (size_t)m * 16 * IN_F);
                float4 u0 = p[0], u1 = p[1];
                uint4 w;
                w.x = pk(u0.x, u0.y); w.y = pk(u0.z, u0.w);
                w.z = pk(u1.x, u1.y); w.w = pk(u1.z, u1.w);
                if (m == 0) a0.u = w; else if (m == 1) a1.u = w;
                else if (m == 2) a2.u = w; else a3.u = w;
            }
        }
        acc0 = __builtin_amdgcn_mfma_f32_16x16x32_bf16(a0.v, bw.v, acc0, 0, 0, 0);
        acc1 = __builtin_amdgcn_mfma_f32_16x16x32_bf16(a1.v, bw.v, acc1, 0, 0, 0);
        acc2 = __builtin_amdgcn_mfma_f32_16x16x32_bf16(a2.v, bw.v, acc2, 0, 0, 0);
        acc3 = __builtin_amdgcn_mfma_f32_16x16x32_bf16(a3.v, bw.v, acc3, 0, 0, 0);
    }

    // store: D[row=(lane>>4)*4+reg][col=lane&15];  token = tok_base + m*16 + kg*4 + reg
    const int feat = (row << 4) + orow;
#pragma unroll
    for (int m = 0; m < 4; ++m) {
        f32x4 a = (m == 0) ? acc0 : (m == 1) ? acc1 : (m == 2) ? acc2 : acc3;
        size_t tok = (size_t)(tok_base + m * 16 + (kg << 2));
        float* op = out + tok * OUT_F + feat;
        op[0 * OUT_F] = a[0];
        op[1 * OUT_F] = a[1];
        op[2 * OUT_F] = a[2];
        op[3 * OUT_F] = a[3];
    }
}

extern "C" void kernel_launch(void* const* d_in, const int* in_sizes, int n_in,
                              void* d_out, int out_size, void* d_ws, size_t ws_size,
                              hipStream_t stream) {
    const float* x      = (const float*)d_in[0];
    const float* sb     = (const float*)d_in[1];
    const int*   rowptr = (const int*)d_in[2];
    const int*   colidx = (const int*)d_in[3];
    const float* bias   = (const float*)d_in[4];
    float* out = (float*)d_out;

    const size_t need = (size_t)TOKENS * IN_F * 2;   // 16 MB bf16 x
    if (ws_size >= need) {
        uint4* xb = (uint4*)d_ws;
        xprep_kernel<<<dim3(2048), dim3(256), 0, stream>>>(x, xb);
        bsl_kernel<true><<<dim3(2048), dim3(256), 0, stream>>>(xb, sb, rowptr, colidx, bias, out);
    } else {
        bsl_kernel<false><<<dim3(2048), dim3(256), 0, stream>>>(x, sb, rowptr, colidx, bias, out);
    }
}